// Round 8
// baseline (228.178 us; speedup 1.0000x reference)
//
#include <hip/hip_runtime.h>
#include <hip/hip_bf16.h>

#define D 128

typedef short bf16x8 __attribute__((ext_vector_type(8)));
typedef float f32x4  __attribute__((ext_vector_type(4)));

__device__ __forceinline__ float bflo(unsigned u) { return __uint_as_float(u << 16); }
__device__ __forceinline__ float bfhi(unsigned u) { return __uint_as_float(u & 0xffff0000u); }
__device__ __forceinline__ unsigned f2bf(float f) {
    unsigned u = __float_as_uint(f);
    return (u + 0x7fffu + ((u >> 16) & 1u)) >> 16;   // RNE
}

// merged pre-pass, range-split by blockIdx:
//   [0, nb)          : copy x -> out2 ; pack x -> bf16 Xb
//   [nb, nb+128)     : W1,W2 (f32 [k][n]) -> Wt1,Wt2 (bf16 [n][k])
//   [nb+128, +cb)    : degree count atomics (cnt pre-zeroed by memset)
__global__ __launch_bounds__(256) void k_pre(
    const float4* __restrict__ x4, float4* __restrict__ out2, uint2* __restrict__ Xb2,
    const float* __restrict__ W1, const float* __restrict__ W2,
    ushort* __restrict__ Wt1, ushort* __restrict__ Wt2,
    const int* __restrict__ dst, int* __restrict__ cnt,
    int n4, int ne, int nb) {
    const int blk = blockIdx.x, t = threadIdx.x;
    if (blk < nb) {
        int i = blk * 256 + t;
        if (i < n4) {
            float4 v = x4[i];
            out2[i] = v;
            uint2 p;
            p.x = f2bf(v.x) | (f2bf(v.y) << 16);
            p.y = f2bf(v.z) | (f2bf(v.w) << 16);
            Xb2[i] = p;
        }
    } else if (blk < nb + 128) {
        int i = (blk - nb) * 256 + t;          // 0..32767
        const float* W = (i < 16384) ? W1 : W2;
        ushort* Wt = (i < 16384) ? Wt1 : Wt2;
        int j = i & 16383;
        int n = j >> 7, k = j & 127;
        Wt[n * 128 + k] = (ushort)f2bf(W[k * 128 + n]);
    } else {
        int e = (blk - nb - 128) * 256 + t;
        if (e < ne) atomicAdd(&cnt[dst[e]], 1);
    }
}

// phase 1: per-block (256 nodes) sum of padded degrees
__global__ __launch_bounds__(256) void k_scan1(const int* __restrict__ cnt,
                                               int* __restrict__ partials, int n) {
    int i = blockIdx.x * 256 + threadIdx.x;
    int v = (i < n) ? ((cnt[i] + 4) & ~3) : 0;   // deg + self, round up to 4
#pragma unroll
    for (int off = 32; off >= 1; off >>= 1) v += __shfl_down(v, off, 64);
    __shared__ int red[4];
    int wid = threadIdx.x >> 6, lane = threadIdx.x & 63;
    if (lane == 0) red[wid] = v;
    __syncthreads();
    if (threadIdx.x == 0) partials[blockIdx.x] = red[0] + red[1] + red[2] + red[3];
}

// phase 2+3 merged: every block redundantly scans the <=256 partials in LDS,
// then local node scan; writes rowptr, dis, self-edge pair, pads, cursor
__global__ __launch_bounds__(256) void k_scan3(
    const int* __restrict__ cnt, const int* __restrict__ partials,
    int* __restrict__ rowptr, float* __restrict__ dis, int* __restrict__ cur,
    int2* __restrict__ ew, int n, int nblk) {
    __shared__ int sp[256];
    __shared__ int s[256];
    const int t = threadIdx.x;
    int pv = (t < nblk) ? partials[t] : 0;
    sp[t] = pv;
    __syncthreads();
    for (int off = 1; off < 256; off <<= 1) {
        int a = (t >= off) ? sp[t - off] : 0;
        __syncthreads();
        sp[t] += a;
        __syncthreads();
    }
    int i = blockIdx.x * 256 + t;
    int deg = (i < n) ? cnt[i] : 0;
    int pdeg = (i < n) ? ((deg + 4) & ~3) : 0;
    s[t] = pdeg;
    __syncthreads();
    for (int off = 1; off < 256; off <<= 1) {
        int a = (t >= off) ? s[t - off] : 0;
        __syncthreads();
        s[t] += a;
        __syncthreads();
    }
    int base = sp[blockIdx.x] - partials[blockIdx.x];   // exclusive block prefix
    if (i < n) {
        int rp = base + s[t] - pdeg;
        rowptr[i] = rp;
        float di = rsqrtf((float)deg + 1.0f);
        dis[i] = di;
        ew[rp] = make_int2(i, __float_as_int(di * di));   // self loop
        cur[i] = 1;
        for (int p = deg + 1; p < pdeg; ++p)              // <=3 pad slots
            ew[rp + p] = make_int2(0, 0);
        if (i == n - 1) rowptr[n] = rp + pdeg;
    }
}

__global__ void k_fill(const int* __restrict__ ei, const int* __restrict__ rowptr,
                       const float* __restrict__ dis, int* __restrict__ cur,
                       int2* __restrict__ ew, int ne) {
    int e = blockIdx.x * blockDim.x + threadIdx.x;
    if (e >= ne) return;
    int s = ei[e];
    int d = ei[ne + e];
    int p = rowptr[d] + atomicAdd(&cur[d], 1);
    ew[p] = make_int2(s, __float_as_int(dis[s] * dis[d]));
}

// Fused layer. Gather phase uses HALF-WAVE row splitting: lanes 0-31 handle
// even edges, 32-63 odd edges; each lane loads uint2 (4 bf16 features, 8B).
// One VMEM instruction covers TWO edge rows. __shfl_xor(32) merges halves.
template <bool BF16OUT>
__global__ __launch_bounds__(256) void k_layer(
    const int* __restrict__ rowptr, const int2* __restrict__ ew,
    const uint* __restrict__ Ain, const ushort* __restrict__ Wt,
    const float* __restrict__ bias, void* __restrict__ out, int n) {
    __shared__ ushort atile[16 * 136];   // bf16 tile, row stride 136 ushorts
    __shared__ float otile[16 * 132];
    const int wid = threadIdx.x >> 6;
    const int lane = threadIdx.x & 63;
    const int h = lane >> 5;         // half: 0 = even edges, 1 = odd edges
    const int li = lane & 31;        // lane-in-half: owns features 4li..4li+3
    const int base = blockIdx.x * 16;
    const int4* ew4 = (const int4*)ew;
    const uint2* Ain2 = (const uint2*)Ain;

#pragma unroll
    for (int j = 0; j < 4; ++j) {
        int node = base + wid * 4 + j;
        float a0 = 0.f, a1 = 0.f, a2 = 0.f, a3 = 0.f;
        if (node < n) {
            int beg = rowptr[node];
            int end = rowptr[node + 1];
            int e = beg;
            for (; e + 8 <= end; e += 8) {
                int4 p0 = ew4[(e >> 1) + 0];
                int4 p1 = ew4[(e >> 1) + 1];
                int4 p2 = ew4[(e >> 1) + 2];
                int4 p3 = ew4[(e >> 1) + 3];
                int s0 = h ? p0.z : p0.x; float w0 = __int_as_float(h ? p0.w : p0.y);
                int s1 = h ? p1.z : p1.x; float w1 = __int_as_float(h ? p1.w : p1.y);
                int s2 = h ? p2.z : p2.x; float w2 = __int_as_float(h ? p2.w : p2.y);
                int s3 = h ? p3.z : p3.x; float w3 = __int_as_float(h ? p3.w : p3.y);
                uint2 q0 = Ain2[(size_t)s0 * 32 + li];
                uint2 q1 = Ain2[(size_t)s1 * 32 + li];
                uint2 q2 = Ain2[(size_t)s2 * 32 + li];
                uint2 q3 = Ain2[(size_t)s3 * 32 + li];
                a0 += w0 * bflo(q0.x) + w1 * bflo(q1.x) + w2 * bflo(q2.x) + w3 * bflo(q3.x);
                a1 += w0 * bfhi(q0.x) + w1 * bfhi(q1.x) + w2 * bfhi(q2.x) + w3 * bfhi(q3.x);
                a2 += w0 * bflo(q0.y) + w1 * bflo(q1.y) + w2 * bflo(q2.y) + w3 * bflo(q3.y);
                a3 += w0 * bfhi(q0.y) + w1 * bfhi(q1.y) + w2 * bfhi(q2.y) + w3 * bfhi(q3.y);
            }
            if (e < end) {   // pad=4 => remainder exactly 4
                int4 p0 = ew4[(e >> 1) + 0];
                int4 p1 = ew4[(e >> 1) + 1];
                int s0 = h ? p0.z : p0.x; float w0 = __int_as_float(h ? p0.w : p0.y);
                int s1 = h ? p1.z : p1.x; float w1 = __int_as_float(h ? p1.w : p1.y);
                uint2 q0 = Ain2[(size_t)s0 * 32 + li];
                uint2 q1 = Ain2[(size_t)s1 * 32 + li];
                a0 += w0 * bflo(q0.x) + w1 * bflo(q1.x);
                a1 += w0 * bfhi(q0.x) + w1 * bfhi(q1.x);
                a2 += w0 * bflo(q0.y) + w1 * bflo(q1.y);
                a3 += w0 * bfhi(q0.y) + w1 * bfhi(q1.y);
            }
        }
        // merge halves (even-edge + odd-edge partial sums)
        a0 += __shfl_xor(a0, 32, 64);
        a1 += __shfl_xor(a1, 32, 64);
        a2 += __shfl_xor(a2, 32, 64);
        a3 += __shfl_xor(a3, 32, 64);
        if (h == 0) {
            uint2 p;
            p.x = f2bf(a0) | (f2bf(a1) << 16);
            p.y = f2bf(a2) | (f2bf(a3) << 16);
            ((uint2*)atile)[(wid * 4 + j) * 34 + li] = p;
        }
    }
    __syncthreads();

    // ---- MFMA phase: wave wid computes col tiles {2*wid, 2*wid+1} ----
    const int m = lane & 15, quad = lane >> 4;
    const ushort* arow = atile + m * 136 + quad * 8;
    bf16x8 afr[4];
#pragma unroll
    for (int kc = 0; kc < 4; ++kc) afr[kc] = *(const bf16x8*)(arow + kc * 32);

    f32x4 acc[2];
#pragma unroll
    for (int t2 = 0; t2 < 2; ++t2) {
        acc[t2] = (f32x4){0.f, 0.f, 0.f, 0.f};
        const int t = wid * 2 + t2;
        const ushort* wrow = Wt + (size_t)(t * 16 + m) * 128 + quad * 8;
#pragma unroll
        for (int kc = 0; kc < 4; ++kc) {
            bf16x8 b = *(const bf16x8*)(wrow + kc * 32);
            acc[t2] = __builtin_amdgcn_mfma_f32_16x16x32_bf16(afr[kc], b, acc[t2], 0, 0, 0);
        }
    }

    // ---- epilogue: bias + tanh -> otile (C/D: row=quad*4+r, col=t*16+m) ----
#pragma unroll
    for (int t2 = 0; t2 < 2; ++t2) {
        const int t = wid * 2 + t2;
        float bb = bias[t * 16 + m];
#pragma unroll
        for (int r = 0; r < 4; ++r)
            otile[(quad * 4 + r) * 132 + t * 16 + m] = tanhf(acc[t2][r] + bb);
    }
    __syncthreads();

    // ---- coalesced store: thread -> (row = tid>>4, seg = tid&15) ----
    const int row = threadIdx.x >> 4, seg = threadIdx.x & 15;
    if (base + row < n) {
        const float* src = &otile[row * 132 + seg * 8];
        if (BF16OUT) {
            uint4 p;
            p.x = f2bf(src[0]) | (f2bf(src[1]) << 16);
            p.y = f2bf(src[2]) | (f2bf(src[3]) << 16);
            p.z = f2bf(src[4]) | (f2bf(src[5]) << 16);
            p.w = f2bf(src[6]) | (f2bf(src[7]) << 16);
            ((uint4*)out)[(size_t)(base + row) * 16 + seg] = p;
        } else {
            float4* dst = (float4*)((float*)out + (size_t)(base + row) * 128 + seg * 8);
            dst[0] = *(const float4*)(src);
            dst[1] = *(const float4*)(src + 4);
        }
    }
}

extern "C" void kernel_launch(void* const* d_in, const int* in_sizes, int n_in,
                              void* d_out, int out_size, void* d_ws, size_t ws_size,
                              hipStream_t stream) {
    const float* x  = (const float*)d_in[0];
    const int*   ei = (const int*)d_in[1];   // [2, E] int32: src then dst
    const float* W1 = (const float*)d_in[2];
    const float* b1 = (const float*)d_in[3];
    const float* W2 = (const float*)d_in[4];
    const float* b2 = (const float*)d_in[5];
    const int N = in_sizes[0] / D;   // 50000
    const int E = in_sizes[1] / 2;   // 500000
    float* out = (float*)d_out;

    char* ws = (char*)d_ws;
    const size_t KB = 1024, MB = 1024 * KB;
    int*    cnt      = (int*)(ws + 0);             // 200KB
    int*    cur      = (int*)(ws + 256 * KB);      // 200KB
    float*  dis      = (float*)(ws + 512 * KB);    // 200KB
    int*    rowptr   = (int*)(ws + 768 * KB);      // 200KB+4
    int*    partials = (int*)(ws + 1000 * KB);     // 1KB
    int2*   ew       = (int2*)(ws + 1 * MB);       // 5.6MB used
    ushort* Xb       = (ushort*)(ws + 9 * MB);     // 12.3MiB
    uint*   H1b      = (uint*)(ws + 22 * MB);      // 12.3MiB
    ushort* Wt1      = (ushort*)(ws + 35 * MB);    // 32KB
    ushort* Wt2      = (ushort*)(ws + 35 * MB + 64 * KB);

    const int n4 = N * D / 4;
    const int nb = (n4 + 255) / 256;              // 6250
    const int cb = (E + 255) / 256;               // 1954
    const int sb = (N + 255) / 256;               // 196
    const int lblocks = (N + 15) / 16;            // 3125

    hipMemsetAsync(cnt, 0, (size_t)N * sizeof(int), stream);
    k_pre<<<nb + 128 + cb, 256, 0, stream>>>(
        (const float4*)x, (float4*)(out + (size_t)N * D), (uint2*)Xb,
        W1, W2, Wt1, Wt2, ei + E, cnt, n4, E, nb);
    k_scan1<<<sb, 256, 0, stream>>>(cnt, partials, N);
    k_scan3<<<sb, 256, 0, stream>>>(cnt, partials, rowptr, dis, cur, ew, N, sb);
    k_fill<<<cb, 256, 0, stream>>>(ei, rowptr, dis, cur, ew, E);

    k_layer<true><<<lblocks, 256, 0, stream>>>(rowptr, ew, (const uint*)Xb, Wt1,
                                               b1, (void*)H1b, N);
    k_layer<false><<<lblocks, 256, 0, stream>>>(rowptr, ew, H1b, Wt2,
                                                b2, (void*)out, N);
}